// Round 4
// baseline (238.538 us; speedup 1.0000x reference)
//
#include <hip/hip_runtime.h>
#include <float.h>
#include <math.h>

#define LL 32
#define BB 128
#define FF 4096
#define EE 512
#define HH 512
#define NLAYER 2
#define KK 20

typedef float f4 __attribute__((ext_vector_type(4)));
typedef short bf16x8 __attribute__((ext_vector_type(8)));
typedef float f32x4 __attribute__((ext_vector_type(4)));

__device__ inline unsigned short bf16rne(float x) {
    unsigned u = __float_as_uint(x);
    u += 0x7fff + ((u >> 16) & 1);
    return (unsigned short)(u >> 16);
}

// ---------------- K1: q mean-pool (blocks 0..255) + W->bf16 conv (blocks 256..767) ----------------
__global__ __launch_bounds__(256) void prep_kernel(const int* __restrict__ tok,
                                                   const float* __restrict__ emb,
                                                   float* __restrict__ q,
                                                   const float* __restrict__ Aw,
                                                   const float* __restrict__ Cw,
                                                   unsigned short* __restrict__ Wbf) {
    int bid = blockIdx.x;
    if (bid < 256) {
        int b = bid >> 1, eh = bid & 1;
        __shared__ int ts[LL];
        if (threadIdx.x < LL) ts[threadIdx.x] = tok[threadIdx.x * BB + b];
        __syncthreads();
        int e = eh * 256 + threadIdx.x;
        float acc = 0.f;
        #pragma unroll
        for (int l = 0; l < LL; ++l) acc += emb[(long)ts[l] * EE + e];
        q[b * EE + e] = acc * (1.0f / LL);
    } else {
        int cid = bid - 256;              // 0..511
        int matY = cid >> 8;              // 0: Aw, 1: Cw
        int blkX = cid & 255;
        const float* W = matY ? Cw : Aw;
        unsigned short* dst = Wbf + (size_t)matY * HH * EE;
        int i = (blkX * 256 + threadIdx.x) * 4;
        float4 v = *(const float4*)(W + i);
        ushort4 o;
        o.x = bf16rne(v.x); o.y = bf16rne(v.y); o.z = bf16rne(v.z); o.w = bf16rne(v.w);
        *(ushort4*)(dst + i) = o;
    }
}

// ---------------- K2: scores[b][f] = dot(q[b], fact[b][f]) ----------------
// wave-per-8-rows; split-butterfly reduce (17 shuffles per 8 rows).
__global__ __launch_bounds__(256) void scores_kernel(const float* __restrict__ q,
                                                     const float* __restrict__ fact,
                                                     float* __restrict__ scores) {
    int b = blockIdx.y;
    int wave = threadIdx.x >> 6;
    int lane = threadIdx.x & 63;
    const f4* qv = (const f4*)(q + b * EE);
    f4 qa = qv[lane];
    f4 qb = qv[64 + lane];
    int f0 = (blockIdx.x * 4 + wave) * 8;
    float d[8];
    #pragma unroll
    for (int i = 0; i < 8; ++i) {
        const f4* fv = (const f4*)(fact + ((long)b * FF + f0 + i) * EE);
        f4 fa = __builtin_nontemporal_load(fv + lane);
        f4 fb = __builtin_nontemporal_load(fv + 64 + lane);
        f4 p = qa * fa + qb * fb;
        d[i] = p.x + p.y + p.z + p.w;
    }
    // stage 1: xor 32 — keep rows 0-3 (lo) / 4-7 (hi)
    bool h32 = lane & 32;
    float e0, e1, e2, e3;
    {
        float s0 = __shfl_xor(d[0], 32), s1 = __shfl_xor(d[1], 32);
        float s2 = __shfl_xor(d[2], 32), s3 = __shfl_xor(d[3], 32);
        float s4 = __shfl_xor(d[4], 32), s5 = __shfl_xor(d[5], 32);
        float s6 = __shfl_xor(d[6], 32), s7 = __shfl_xor(d[7], 32);
        e0 = h32 ? d[4] + s4 : d[0] + s0;
        e1 = h32 ? d[5] + s5 : d[1] + s1;
        e2 = h32 ? d[6] + s6 : d[2] + s2;
        e3 = h32 ? d[7] + s7 : d[3] + s3;
    }
    // stage 2: xor 16
    bool h16 = lane & 16;
    float g0, g1;
    {
        float s0 = __shfl_xor(e0, 16), s1 = __shfl_xor(e1, 16);
        float s2 = __shfl_xor(e2, 16), s3 = __shfl_xor(e3, 16);
        g0 = h16 ? e2 + s2 : e0 + s0;
        g1 = h16 ? e3 + s3 : e1 + s1;
    }
    // stage 3: xor 8
    bool h8 = lane & 8;
    float hs;
    {
        float s0 = __shfl_xor(g0, 8), s1 = __shfl_xor(g1, 8);
        hs = h8 ? g1 + s1 : g0 + s0;
    }
    hs += __shfl_xor(hs, 4);
    hs += __shfl_xor(hs, 2);
    hs += __shfl_xor(hs, 1);
    // lane bits [5:3] encode the row
    if ((lane & 7) == 0) scores[b * FF + f0 + ((lane >> 3) & 7)] = hs;
}

// ---------------- K3: top-20 + gather + update(h,c) + fact_M/C MFMA (fully fused, block per b) ----------------
__global__ __launch_bounds__(256) void fused_kernel(const float* __restrict__ scores,
                                                    const float* __restrict__ fact,
                                                    const float* __restrict__ hin,
                                                    const float* __restrict__ cin,
                                                    const unsigned short* __restrict__ Wbf,
                                                    const float* __restrict__ Ab,
                                                    const float* __restrict__ Cb,
                                                    float* __restrict__ out) {
    int b = blockIdx.x;
    __shared__ float vals[FF];                  // 16 KiB
    __shared__ float tf[KK][EE];                // 40 KiB (f32, for update)
    __shared__ unsigned short tfb[32 * EE];     // 32 KiB (bf16 swizzled, for MFMA)
    __shared__ unsigned long long wbest[4];
    __shared__ int sel[KK];
    int t = threadIdx.x;
    int wave = t >> 6, lane = t & 63;

    // stage scores
    const float4* sv = (const float4*)(scores + b * FF);
    float4* vv = (float4*)vals;
    for (int i = t; i < FF / 4; i += 256) vv[i] = sv[i];
    // zero-fill tfb rows 20..31 (12 KiB) while we're here
    {
        float4 z = {0, 0, 0, 0};
        for (int i = t; i < 12 * 1024 / 16; i += 256)
            *(float4*)((char*)tfb + 20 * 1024 + i * 16) = z;
    }
    __syncthreads();

    // 20 x argmax, packed (sortable-value | (FF-1-idx)); ties -> lower idx
    for (int it = 0; it < KK; ++it) {
        unsigned long long best = 0;
        #pragma unroll
        for (int s = 0; s < FF / 256; ++s) {
            int j = t + s * 256;
            unsigned u = __float_as_uint(vals[j]);
            u ^= ((int)u >> 31) | 0x80000000u;
            unsigned long long key = ((unsigned long long)u << 32) | (unsigned)(FF - 1 - j);
            if (key > best) best = key;
        }
        #pragma unroll
        for (int off = 32; off > 0; off >>= 1) {
            unsigned hi = (unsigned)(best >> 32), lo = (unsigned)best;
            unsigned ohi = __shfl_xor(hi, off, 64);
            unsigned olo = __shfl_xor(lo, off, 64);
            unsigned long long o = ((unsigned long long)ohi << 32) | olo;
            if (o > best) best = o;
        }
        if (lane == 0) wbest[wave] = best;
        __syncthreads();
        if (t == 0) {
            unsigned long long bb = wbest[0];
            if (wbest[1] > bb) bb = wbest[1];
            if (wbest[2] > bb) bb = wbest[2];
            if (wbest[3] > bb) bb = wbest[3];
            int idx = FF - 1 - (int)(bb & 0xFFFFFFFFu);
            sel[it] = idx;
            vals[idx] = -FLT_MAX;
        }
        __syncthreads();
    }

    // gather 20 rows -> tf (f32) and tfb (bf16, XOR-swizzled)
    for (int kk = 0; kk < KK; kk += 2) {
        int k = kk + (t >> 7);
        int e = t & 127;                         // float4 index within row
        int src = sel[k];
        float4 v = *(const float4*)(fact + (((long)b * FF + src) * EE) + e * 4);
        *(float4*)&tf[k][e * 4] = v;
        ushort4 o;
        o.x = bf16rne(v.x); o.y = bf16rne(v.y); o.z = bf16rne(v.z); o.w = bf16rne(v.w);
        int byte = (k * 1024 + e * 8) ^ ((k & 7) << 4);
        *(ushort4*)((char*)tfb + byte) = o;
    }
    __syncthreads();

    // ---- update: wave w -> (u = h if w<2 else c, layer = w&1) ----
    {
        const float* u = (wave < 2 ? hin : cin) + ((size_t)(wave & 1) * BB + b) * EE;
        const float4* uv = (const float4*)u;
        float4 ua = uv[lane], ub = uv[64 + lane];
        float sk[KK];
        #pragma unroll
        for (int k = 0; k < KK; ++k) {
            const float4* tv = (const float4*)&tf[k][0];
            float4 ta = tv[lane], tb = tv[64 + lane];
            float d = ua.x * ta.x + ua.y * ta.y + ua.z * ta.z + ua.w * ta.w
                    + ub.x * tb.x + ub.y * tb.y + ub.z * tb.z + ub.w * tb.w;
            #pragma unroll
            for (int off = 32; off > 0; off >>= 1) d += __shfl_xor(d, off, 64);
            sk[k] = d;
        }
        float m = sk[0];
        #pragma unroll
        for (int k = 1; k < KK; ++k) m = fmaxf(m, sk[k]);
        float sum = 0.f;
        #pragma unroll
        for (int k = 0; k < KK; ++k) { sk[k] = __expf(sk[k] - m); sum += sk[k]; }
        float inv = 1.f / sum;
        float4 oa = {0, 0, 0, 0}, ob = {0, 0, 0, 0};
        #pragma unroll
        for (int k = 0; k < KK; ++k) {
            float p = sk[k] * inv;
            const float4* tv = (const float4*)&tf[k][0];
            float4 ta = tv[lane], tb = tv[64 + lane];
            oa.x += p * ta.x; oa.y += p * ta.y; oa.z += p * ta.z; oa.w += p * ta.w;
            ob.x += p * tb.x; ob.y += p * tb.y; ob.z += p * tb.z; ob.w += p * tb.w;
        }
        oa.x += ua.x; oa.y += ua.y; oa.z += ua.z; oa.w += ua.w;
        ob.x += ub.x; ob.y += ub.y; ob.z += ub.z; ob.w += ub.w;
        float* obase = out + (size_t)(wave < 2 ? 0 : NLAYER * BB * HH)
                           + ((size_t)(wave & 1) * BB + b) * HH;
        float4* ov = (float4*)obase;
        ov[lane] = oa;
        ov[64 + lane] = ob;
    }

    // ---- fact_M / fact_C via MFMA; wave owns 128 h-cols, loops over both mats ----
    {
        int lrow = lane & 15, lk = lane >> 4;
        for (int mat = 0; mat < 2; ++mat) {
            const unsigned short* W = Wbf + (size_t)mat * HH * EE;
            const float* bias = mat ? Cb : Ab;
            float* O = out + (size_t)2 * NLAYER * BB * HH
                           + (size_t)mat * BB * KK * HH + (size_t)b * KK * HH;
            f32x4 acc[2][8];
            #pragma unroll
            for (int m = 0; m < 2; ++m)
                #pragma unroll
                for (int n = 0; n < 8; ++n) acc[m][n] = (f32x4){0, 0, 0, 0};
            const unsigned short* wbase = W + (size_t)(wave * 128 + lrow) * EE + lk * 8;
            #pragma unroll 2
            for (int ks = 0; ks < 16; ++ks) {
                int col2 = (ks * 32 + lk * 8) * 2;
                int byte0 = (lrow * 1024 + col2) ^ ((lrow & 7) << 4);
                bf16x8 a0 = *(const bf16x8*)((const char*)tfb + byte0);
                int r1 = 16 + lrow;
                int byte1 = (r1 * 1024 + col2) ^ ((r1 & 7) << 4);
                bf16x8 a1 = *(const bf16x8*)((const char*)tfb + byte1);
                #pragma unroll
                for (int n = 0; n < 8; ++n) {
                    bf16x8 bfrag = *(const bf16x8*)(wbase + (size_t)n * 16 * EE + ks * 32);
                    acc[0][n] = __builtin_amdgcn_mfma_f32_16x16x32_bf16(a0, bfrag, acc[0][n], 0, 0, 0);
                    acc[1][n] = __builtin_amdgcn_mfma_f32_16x16x32_bf16(a1, bfrag, acc[1][n], 0, 0, 0);
                }
            }
            #pragma unroll
            for (int n = 0; n < 8; ++n) {
                int h = wave * 128 + n * 16 + lrow;
                float bv = bias[h];
                #pragma unroll
                for (int r = 0; r < 4; ++r) {
                    int k0 = lk * 4 + r;
                    O[(size_t)k0 * HH + h] = acc[0][n][r] + bv;
                    int k1 = 16 + lk * 4 + r;
                    if (k1 < KK) O[(size_t)k1 * HH + h] = acc[1][n][r] + bv;
                }
            }
        }
    }
}

extern "C" void kernel_launch(void* const* d_in, const int* in_sizes, int n_in,
                              void* d_out, int out_size, void* d_ws, size_t ws_size,
                              hipStream_t stream) {
    const int* tok = (const int*)d_in[0];
    const float* fact = (const float*)d_in[1];
    const float* hin = (const float*)d_in[2];
    const float* cin = (const float*)d_in[3];
    const float* emb = (const float*)d_in[4];
    const float* Aw = (const float*)d_in[5];
    const float* Ab = (const float*)d_in[6];
    const float* Cw = (const float*)d_in[7];
    const float* Cb = (const float*)d_in[8];
    float* out = (float*)d_out;

    float* ws = (float*)d_ws;
    float* q = ws;                                        // 65536 f
    float* scores = ws + 65536;                           // 524288 f
    unsigned short* Wbf = (unsigned short*)(ws + 65536 + 524288);  // 524288 us

    prep_kernel<<<768, 256, 0, stream>>>(tok, emb, q, Aw, Cw, Wbf);
    scores_kernel<<<dim3(FF / 32, BB), 256, 0, stream>>>(q, fact, scores);
    fused_kernel<<<BB, 256, 0, stream>>>(scores, fact, hin, cin, Wbf, Ab, Cb, out);
}

// Round 5
// 220.468 us; speedup vs baseline: 1.0820x; 1.0820x over previous
//
#include <hip/hip_runtime.h>
#include <float.h>
#include <math.h>

#define LL 32
#define BB 128
#define FF 4096
#define EE 512
#define HH 512
#define NLAYER 2
#define KK 20

typedef float f4 __attribute__((ext_vector_type(4)));
typedef short bf16x8 __attribute__((ext_vector_type(8)));
typedef float f32x4 __attribute__((ext_vector_type(4)));

__device__ inline unsigned short bf16rne(float x) {
    unsigned u = __float_as_uint(x);
    u += 0x7fff + ((u >> 16) & 1);
    return (unsigned short)(u >> 16);
}

// ---------------- K1: q mean-pool (blocks 0..255) + W->bf16 conv (blocks 256..767) ----------------
__global__ __launch_bounds__(256) void prep_kernel(const int* __restrict__ tok,
                                                   const float* __restrict__ emb,
                                                   float* __restrict__ q,
                                                   const float* __restrict__ Aw,
                                                   const float* __restrict__ Cw,
                                                   unsigned short* __restrict__ Wbf) {
    int bid = blockIdx.x;
    if (bid < 256) {
        int b = bid >> 1, eh = bid & 1;
        __shared__ int ts[LL];
        if (threadIdx.x < LL) ts[threadIdx.x] = tok[threadIdx.x * BB + b];
        __syncthreads();
        int e = eh * 256 + threadIdx.x;
        float acc = 0.f;
        #pragma unroll
        for (int l = 0; l < LL; ++l) acc += emb[(long)ts[l] * EE + e];
        q[b * EE + e] = acc * (1.0f / LL);
    } else {
        int cid = bid - 256;              // 0..511
        int matY = cid >> 8;              // 0: Aw, 1: Cw
        int blkX = cid & 255;
        const float* W = matY ? Cw : Aw;
        unsigned short* dst = Wbf + (size_t)matY * HH * EE;
        int i = (blkX * 256 + threadIdx.x) * 4;
        float4 v = *(const float4*)(W + i);
        ushort4 o;
        o.x = bf16rne(v.x); o.y = bf16rne(v.y); o.z = bf16rne(v.z); o.w = bf16rne(v.w);
        *(ushort4*)(dst + i) = o;
    }
}

// ---------------- K2: scores[b][f] = dot(q[b], fact[b][f]) ----------------
// wave-per-8-rows; split-butterfly reduce (17 shuffles per 8 rows).
__global__ __launch_bounds__(256) void scores_kernel(const float* __restrict__ q,
                                                     const float* __restrict__ fact,
                                                     float* __restrict__ scores) {
    int b = blockIdx.y;
    int wave = threadIdx.x >> 6;
    int lane = threadIdx.x & 63;
    const f4* qv = (const f4*)(q + b * EE);
    f4 qa = qv[lane];
    f4 qb = qv[64 + lane];
    int f0 = (blockIdx.x * 4 + wave) * 8;
    float d[8];
    #pragma unroll
    for (int i = 0; i < 8; ++i) {
        const f4* fv = (const f4*)(fact + ((long)b * FF + f0 + i) * EE);
        f4 fa = __builtin_nontemporal_load(fv + lane);
        f4 fb = __builtin_nontemporal_load(fv + 64 + lane);
        f4 p = qa * fa + qb * fb;
        d[i] = p.x + p.y + p.z + p.w;
    }
    bool h32 = lane & 32;
    float e0, e1, e2, e3;
    {
        float s0 = __shfl_xor(d[0], 32), s1 = __shfl_xor(d[1], 32);
        float s2 = __shfl_xor(d[2], 32), s3 = __shfl_xor(d[3], 32);
        float s4 = __shfl_xor(d[4], 32), s5 = __shfl_xor(d[5], 32);
        float s6 = __shfl_xor(d[6], 32), s7 = __shfl_xor(d[7], 32);
        e0 = h32 ? d[4] + s4 : d[0] + s0;
        e1 = h32 ? d[5] + s5 : d[1] + s1;
        e2 = h32 ? d[6] + s6 : d[2] + s2;
        e3 = h32 ? d[7] + s7 : d[3] + s3;
    }
    bool h16 = lane & 16;
    float g0, g1;
    {
        float s0 = __shfl_xor(e0, 16), s1 = __shfl_xor(e1, 16);
        float s2 = __shfl_xor(e2, 16), s3 = __shfl_xor(e3, 16);
        g0 = h16 ? e2 + s2 : e0 + s0;
        g1 = h16 ? e3 + s3 : e1 + s1;
    }
    bool h8 = lane & 8;
    float hs;
    {
        float s0 = __shfl_xor(g0, 8), s1 = __shfl_xor(g1, 8);
        hs = h8 ? g1 + s1 : g0 + s0;
    }
    hs += __shfl_xor(hs, 4);
    hs += __shfl_xor(hs, 2);
    hs += __shfl_xor(hs, 1);
    if ((lane & 7) == 0) scores[b * FF + f0 + ((lane >> 3) & 7)] = hs;
}

// ---------------- K3: top-20 (register keys) + gather + update(h,c) ----------------
__global__ __launch_bounds__(256) void topk_update_kernel(const float* __restrict__ scores,
                                                          const float* __restrict__ fact,
                                                          const float* __restrict__ hin,
                                                          const float* __restrict__ cin,
                                                          unsigned short* __restrict__ topfb,
                                                          float* __restrict__ out) {
    int b = blockIdx.x;
    __shared__ float tf[KK][EE];               // 40 KiB
    __shared__ unsigned long long wbest[4];
    __shared__ unsigned long long wkey_s;
    __shared__ int sel[KK];
    int t = threadIdx.x;
    int wave = t >> 6, lane = t & 63;

    // build 16 packed keys in registers; thread owns float4 slots {t+256s}
    unsigned long long keys[16];
    {
        const float4* sv = (const float4*)(scores + b * FF);
        #pragma unroll
        for (int s = 0; s < 4; ++s) {
            float4 v = sv[t + 256 * s];
            float vc[4] = {v.x, v.y, v.z, v.w};
            #pragma unroll
            for (int c = 0; c < 4; ++c) {
                int idx = 4 * (t + 256 * s) + c;
                unsigned u = __float_as_uint(vc[c]);
                u ^= ((int)u >> 31) | 0x80000000u;
                keys[s * 4 + c] = ((unsigned long long)u << 32) | (unsigned)(FF - 1 - idx);
            }
        }
    }

    // 20 iterations: reg max -> wave butterfly -> block -> knock out winner
    for (int it = 0; it < KK; ++it) {
        unsigned long long best = keys[0];
        #pragma unroll
        for (int i = 1; i < 16; ++i) best = keys[i] > best ? keys[i] : best;
        #pragma unroll
        for (int off = 32; off > 0; off >>= 1) {
            unsigned long long o = __shfl_xor(best, off, 64);
            if (o > best) best = o;
        }
        if (lane == 0) wbest[wave] = best;
        __syncthreads();
        if (t == 0) {
            unsigned long long bb = wbest[0];
            if (wbest[1] > bb) bb = wbest[1];
            if (wbest[2] > bb) bb = wbest[2];
            if (wbest[3] > bb) bb = wbest[3];
            wkey_s = bb;
            sel[it] = FF - 1 - (int)(bb & 0xFFFFFFFFu);
        }
        __syncthreads();
        unsigned long long wk = wkey_s;
        #pragma unroll
        for (int i = 0; i < 16; ++i)
            if (keys[i] == wk) keys[i] = 0;
    }

    // gather 20 rows -> tf (f32 LDS) and topfb (bf16 global)
    for (int kk = 0; kk < KK; kk += 2) {
        int k = kk + (t >> 7);
        int e = t & 127;
        int src = sel[k];
        float4 v = *(const float4*)(fact + (((long)b * FF + src) * EE) + e * 4);
        *(float4*)&tf[k][e * 4] = v;
        ushort4 o;
        o.x = bf16rne(v.x); o.y = bf16rne(v.y); o.z = bf16rne(v.z); o.w = bf16rne(v.w);
        *(ushort4*)(topfb + ((size_t)b * KK + k) * EE + e * 4) = o;
    }
    __syncthreads();

    // update: wave w -> (u = h if w<2 else c, layer = w&1)
    const float* u = (wave < 2 ? hin : cin) + ((size_t)(wave & 1) * BB + b) * EE;
    const float4* uv = (const float4*)u;
    float4 ua = uv[lane], ub = uv[64 + lane];
    float sk[KK];
    #pragma unroll
    for (int k = 0; k < KK; ++k) {
        const float4* tv = (const float4*)&tf[k][0];
        float4 ta = tv[lane], tb = tv[64 + lane];
        float d = ua.x * ta.x + ua.y * ta.y + ua.z * ta.z + ua.w * ta.w
                + ub.x * tb.x + ub.y * tb.y + ub.z * tb.z + ub.w * tb.w;
        #pragma unroll
        for (int off = 32; off > 0; off >>= 1) d += __shfl_xor(d, off, 64);
        sk[k] = d;
    }
    float m = sk[0];
    #pragma unroll
    for (int k = 1; k < KK; ++k) m = fmaxf(m, sk[k]);
    float sum = 0.f;
    #pragma unroll
    for (int k = 0; k < KK; ++k) { sk[k] = __expf(sk[k] - m); sum += sk[k]; }
    float inv = 1.f / sum;
    float4 oa = {0, 0, 0, 0}, ob = {0, 0, 0, 0};
    #pragma unroll
    for (int k = 0; k < KK; ++k) {
        float p = sk[k] * inv;
        const float4* tv = (const float4*)&tf[k][0];
        float4 ta = tv[lane], tb = tv[64 + lane];
        oa.x += p * ta.x; oa.y += p * ta.y; oa.z += p * ta.z; oa.w += p * ta.w;
        ob.x += p * tb.x; ob.y += p * tb.y; ob.z += p * tb.z; ob.w += p * tb.w;
    }
    oa.x += ua.x; oa.y += ua.y; oa.z += ua.z; oa.w += ua.w;
    ob.x += ub.x; ob.y += ub.y; ob.z += ub.z; ob.w += ub.w;
    float* obase = out + (size_t)(wave < 2 ? 0 : NLAYER * BB * HH)
                       + ((size_t)(wave & 1) * BB + b) * HH;
    float4* ov = (float4*)obase;
    ov[lane] = oa;
    ov[64 + lane] = ob;
}

// ---------------- K4: fact_M / fact_C via bf16 MFMA (standalone, 256 blocks) ----------------
__global__ __launch_bounds__(256) void factmc_kernel(const unsigned short* __restrict__ topfb,
                                                     const unsigned short* __restrict__ Wbf,
                                                     const float* __restrict__ Ab,
                                                     const float* __restrict__ Cb,
                                                     float* __restrict__ out) {
    int b = blockIdx.x, mat = blockIdx.y;
    const unsigned short* W = Wbf + (size_t)mat * HH * EE;
    const float* bias = mat ? Cb : Ab;
    float* O = out + (size_t)2 * NLAYER * BB * HH
                   + (size_t)mat * BB * KK * HH + (size_t)b * KK * HH;

    __shared__ unsigned short tf[32 * EE];   // 32 KiB; rows 20..31 uninit (never stored)
    {
        const unsigned short* src = topfb + (size_t)b * KK * EE;
        for (int ib = threadIdx.x; ib < KK * EE / 8; ib += 256) {
            int row = ib >> 6;
            int cb = ib & 63;
            float4 v = *(const float4*)(src + row * EE + cb * 8);
            int byte = (row * 1024 + cb * 16) ^ ((row & 7) << 4);
            *(float4*)((char*)tf + byte) = v;
        }
    }
    __syncthreads();

    int wave = threadIdx.x >> 6, lane = threadIdx.x & 63;
    int lrow = lane & 15, lk = lane >> 4;
    f32x4 acc[2][8];
    #pragma unroll
    for (int m = 0; m < 2; ++m)
        #pragma unroll
        for (int n = 0; n < 8; ++n) acc[m][n] = (f32x4){0, 0, 0, 0};

    const unsigned short* wbase = W + (size_t)(wave * 128 + lrow) * EE + lk * 8;

    #pragma unroll 2
    for (int ks = 0; ks < 16; ++ks) {
        int col2 = (ks * 32 + lk * 8) * 2;
        int byte0 = (lrow * 1024 + col2) ^ ((lrow & 7) << 4);
        bf16x8 a0 = *(const bf16x8*)((const char*)tf + byte0);
        int r1 = 16 + lrow;
        int byte1 = (r1 * 1024 + col2) ^ ((r1 & 7) << 4);
        bf16x8 a1 = *(const bf16x8*)((const char*)tf + byte1);
        #pragma unroll
        for (int n = 0; n < 8; ++n) {
            bf16x8 bfrag = *(const bf16x8*)(wbase + (size_t)n * 16 * EE + ks * 32);
            acc[0][n] = __builtin_amdgcn_mfma_f32_16x16x32_bf16(a0, bfrag, acc[0][n], 0, 0, 0);
            acc[1][n] = __builtin_amdgcn_mfma_f32_16x16x32_bf16(a1, bfrag, acc[1][n], 0, 0, 0);
        }
    }

    #pragma unroll
    for (int n = 0; n < 8; ++n) {
        int h = wave * 128 + n * 16 + lrow;
        float bv = bias[h];
        #pragma unroll
        for (int r = 0; r < 4; ++r) {
            int k0 = lk * 4 + r;
            O[(size_t)k0 * HH + h] = acc[0][n][r] + bv;
            int k1 = 16 + lk * 4 + r;
            if (k1 < KK) O[(size_t)k1 * HH + h] = acc[1][n][r] + bv;
        }
    }
}

extern "C" void kernel_launch(void* const* d_in, const int* in_sizes, int n_in,
                              void* d_out, int out_size, void* d_ws, size_t ws_size,
                              hipStream_t stream) {
    const int* tok = (const int*)d_in[0];
    const float* fact = (const float*)d_in[1];
    const float* hin = (const float*)d_in[2];
    const float* cin = (const float*)d_in[3];
    const float* emb = (const float*)d_in[4];
    const float* Aw = (const float*)d_in[5];
    const float* Ab = (const float*)d_in[6];
    const float* Cw = (const float*)d_in[7];
    const float* Cb = (const float*)d_in[8];
    float* out = (float*)d_out;

    float* ws = (float*)d_ws;
    float* q = ws;                                                     // 65536 f
    float* scores = ws + 65536;                                        // 524288 f
    unsigned short* topfb = (unsigned short*)(ws + 65536 + 524288);    // 1310720 us
    unsigned short* Wbf = (unsigned short*)(ws + 65536 + 524288 + 655360); // 524288 us

    prep_kernel<<<768, 256, 0, stream>>>(tok, emb, q, Aw, Cw, Wbf);
    scores_kernel<<<dim3(FF / 32, BB), 256, 0, stream>>>(q, fact, scores);
    topk_update_kernel<<<BB, 256, 0, stream>>>(scores, fact, hin, cin, topfb, out);
    factmc_kernel<<<dim3(BB, 2), 256, 0, stream>>>(topfb, Wbf, Ab, Cb, out);
}